// Round 6
// baseline (82.832 us; speedup 1.0000x reference)
//
#include <hip/hip_runtime.h>

// CARAFE: features [B=2, h=64, w=64, C0=256] f32, masks [B, H=128, W=128, 25] f32,
// k=5, group=1. Nearest-upsample (half-pixel, 2x) == Y//2.
// out[b,Y,X,c] = sum_{di,dj} M[b,Y,X,di*5+dj] * F[b, Y/2+di-2, X/2+dj-2, c] (zero pad).
//
// R6 (= R5 with the nontemporal-store type fixed):
//  - Wave64 = 2 x-adjacent low-res pixels (2x4 output pixels); tap union 5x6
//    float4 loads per wave. Lane i covers channels 4i..4i+3.
//  - Row-wise software pipeline: tap-row di+1 prefetched into registers while
//    row di's FMAs run -> >=6 loads in flight to hide cold HBM latency (the
//    256 MiB 0xAA ws-poison flushes caches before every replay).
//  - Nontemporal output stores via clang ext_vector_type (HIP float4 is a
//    class type and __builtin_nontemporal_store rejects it -- R5 compile fail).
//  - All coordinates wave-uniform scalar (readfirstlane); body branchless
//    (clamp + 0/1 scale). Runtime exec-mask predication failed post-timing
//    re-validation in R1; never again.

#define C0   256
#define HLO  64
#define WLO  64
#define HHI  128
#define WHI  128
#define K    5
#define KK   25

typedef float vf4 __attribute__((ext_vector_type(4)));

__global__ __launch_bounds__(256) void carafe_kernel(
    const float* __restrict__ feat,   // [B, 64, 64, 256]
    const float* __restrict__ mask,   // [B, 128, 128, 25]
    float* __restrict__ out)          // [B, 128, 128, 256]
{
    // --- scalar (wave-uniform) tile coordinates ---
    const int wv   = __builtin_amdgcn_readfirstlane(threadIdx.x >> 6); // 0..3
    const int bid  = blockIdx.x;          // 0..1023
    const int xcd  = bid & 7;
    const int i    = bid >> 3;            // 0..127
    const int r    = xcd * 16 + (i & 15); // global row 0..127
    const int xblk = i >> 4;              // 0..7
    const int b    = r >> 6;
    const int y0   = r & 63;
    const int x0   = xblk * 8 + wv * 2;   // low-res col of first quad
    const int lane = threadIdx.x & 63;
    const int c    = lane * 4;

    const int Y0 = y0 * 2;
    const int X0 = x0 * 2;

    const float* fbase = feat + (size_t)b * HLO * WLO * C0 + c;
    const float* mrow0 = mask + (size_t)((b * HHI + Y0) * WHI + X0) * KK;
    const float* mrow1 = mrow0 + WHI * KK;

    // Per-column clamped offsets + validity (wave-uniform, loop-invariant).
    int   xoff[6];
    float vx[6];
    #pragma unroll
    for (int t = 0; t < 6; ++t) {
        const int x = x0 + t - 2;
        xoff[t] = min(max(x, 0), WLO - 1);
        vx[t]   = ((unsigned)x < (unsigned)WLO) ? 1.f : 0.f;
    }

    // acc[row][qq]: output pixel (Y0+row, X0+qq), 4 channels each.
    vf4 acc[2][4];
    #pragma unroll
    for (int rr = 0; rr < 2; ++rr)
        #pragma unroll
        for (int qq = 0; qq < 4; ++qq)
            acc[rr][qq] = (vf4){0.f, 0.f, 0.f, 0.f};

    // --- software pipeline over tap rows ---
    vf4   fc[6];    // current row taps
    float vyc;      // current row validity

    {   // prologue: load row di=0 (y = y0-2)
        const int y  = y0 - 2;
        const int yc = min(max(y, 0), HLO - 1);
        vyc = ((unsigned)y < (unsigned)HLO) ? 1.f : 0.f;
        const float* rbase = fbase + (size_t)yc * WLO * C0;
        #pragma unroll
        for (int t = 0; t < 6; ++t)
            fc[t] = *(const vf4*)(rbase + (size_t)xoff[t] * C0);
    }

    #pragma unroll
    for (int di = 0; di < K; ++di) {
        // prefetch next row while computing this one
        vf4   fn[6];
        float vyn = 0.f;
        if (di < K - 1) {
            const int y  = y0 + di - 1;       // (di+1) - 2
            const int yc = min(max(y, 0), HLO - 1);
            vyn = ((unsigned)y < (unsigned)HLO) ? 1.f : 0.f;
            const float* rbase = fbase + (size_t)yc * WLO * C0;
            #pragma unroll
            for (int t = 0; t < 6; ++t)
                fn[t] = *(const vf4*)(rbase + (size_t)xoff[t] * C0);
        }

        // compute with current row
        #pragma unroll
        for (int t = 0; t < 6; ++t) {
            const float v = vyc * vx[t];
            vf4 f = fc[t] * v;

            if (t <= 4) {                     // quad 0: dj = t
                const int p = di * K + t;
                #pragma unroll
                for (int rr = 0; rr < 2; ++rr) {
                    const float* mr = rr ? mrow1 : mrow0;
                    #pragma unroll
                    for (int qq = 0; qq < 2; ++qq) {
                        const float w = mr[qq * KK + p];
                        acc[rr][qq] += f * w;
                    }
                }
            }
            if (t >= 1) {                     // quad 1: dj = t-1
                const int p = di * K + t - 1;
                #pragma unroll
                for (int rr = 0; rr < 2; ++rr) {
                    const float* mr = rr ? mrow1 : mrow0;
                    #pragma unroll
                    for (int qq = 2; qq < 4; ++qq) {
                        const float w = mr[qq * KK + p];
                        acc[rr][qq] += f * w;
                    }
                }
            }
        }

        // rotate (renamed away after full unroll)
        #pragma unroll
        for (int t = 0; t < 6; ++t) fc[t] = fn[t];
        vyc = vyn;
    }

    float* ob = out + (size_t)((b * HHI + Y0) * WHI + X0) * C0 + c;
    #pragma unroll
    for (int rr = 0; rr < 2; ++rr)
        #pragma unroll
        for (int qq = 0; qq < 4; ++qq)
            __builtin_nontemporal_store(acc[rr][qq],
                (vf4*)(ob + (size_t)(rr * WHI + qq) * C0));
}

extern "C" void kernel_launch(void* const* d_in, const int* in_sizes, int n_in,
                              void* d_out, int out_size, void* d_ws, size_t ws_size,
                              hipStream_t stream) {
    const float* feat = (const float*)d_in[0];   // 2*64*64*256
    const float* mask = (const float*)d_in[1];   // 2*128*128*25
    float* out = (float*)d_out;                  // 2*128*128*256

    // 2 batches * 64 rows * 8 x-blocks = 1024 blocks; 4 waves/block,
    // each wave = 2 low-res pixels (2x4 output pixels).
    carafe_kernel<<<1024, 256, 0, stream>>>(feat, mask, out);
}